// Round 18
// baseline (1383.513 us; speedup 1.0000x reference)
//
#include <hip/hip_runtime.h>
#include <hip/hip_bf16.h>

// StackedFlow v16 = v14 (r16 winner, 1136us) + ONLY the exp2-prefold (isolated A/B).
// r17's bundle (exp2 + aw0->L2 + hoist) regressed to 1377us: WRITE 38->48MB (live-range
// growth), G1 A-frags on per-eval L2 latency path. v16 keeps v14's structure byte-for-byte
// (aw0 in regs, unhoisted G1 bias) and changes only: ODE W0/W1/b0/b1/trow pre-scaled by
// 2*log2(e) so tanh = 1-2*rcp(exp2(v)+1) drops the per-tanh log2e multiply that __expf
// emits (32 VALU/thread/eval). Exact in fp32. Predict 1080-1120us; else v14 is the plateau.

#define LNUM   4
#define NSTEP  8
#define EPSV   1e-3f
#define TSCL   2.8853900817779268f   // 2*log2(e)

typedef __attribute__((ext_vector_type(8))) short  short8;
typedef __attribute__((ext_vector_type(4))) float  floatx4;

#define MF(a, b, c) __builtin_amdgcn_mfma_f32_16x16x32_bf16((a), (b), (c), 0, 0, 0)

// d_ws layout (bf16 element offsets), per-GEMM fragment arrays [layer][nt*KS+ks][lane][8]
#define OW0_OFF 0        // ode W0 rows 1..64  (64 x 256)  PRE-SCALED x 2log2e
#define OW1_OFF 65536    // ode W1            (256 x 256)  PRE-SCALED x 2log2e
#define OW2_OFF 327680   // ode W2            (256 x 64)
#define NW0_OFF 393216   // nvp W0            (32 x 256)
#define NW1_OFF 425984   // nvp W1            (256 x 256)
#define NW2_OFF 688128   // nvp W2            (256 x 64)
#define WS_ELEMS 753664

// LDS byte offsets (64-row tile, 75.3KB)
#define H1_OFF   0        // 32K bf16 [64][256] RS=512 swz((m&15)<<4); first 4K aliases shf
#define H2_OFF   32768    // 32K bf16 [64][256] RS=512 swz((m&15)<<4)
#define YIN_OFF  65536    // 8K  bf16 [64][64]  RS=128 swz((m&7)<<4); NVP: x0 lo, x1 hi half-row
#define PARS_OFF 73728    // 3328B: b0 | b1(+256) | b2(+512) | w0row0(+576)
#define LDS_SIZE 77056

__device__ __forceinline__ unsigned short f2bfu_rne(float f) {
  unsigned int u = __float_as_uint(f);
  return (unsigned short)((u + 0x7FFFu + ((u >> 16) & 1u)) >> 16);  // RNE (prep only)
}

__device__ __forceinline__ unsigned long long pack4bf(float a, float b, float c, float d) {
  __hip_bfloat162 lo = __float22bfloat162_rn(make_float2(a, b));
  __hip_bfloat162 hi = __float22bfloat162_rn(make_float2(c, d));
  unsigned int ul, uh;
  __builtin_memcpy(&ul, &lo, 4);
  __builtin_memcpy(&uh, &hi, 4);
  return (unsigned long long)ul | ((unsigned long long)uh << 32);
}

__device__ __forceinline__ float bfu2f(unsigned short u) {
  return __uint_as_float((unsigned int)u << 16);
}

// input v is ALREADY 2*log2(e) x the mathematical pre-activation -> e^{2x} = 2^v
__device__ __forceinline__ float tanh_fast2(float v) {
  float e = exp2f(v);
  return 1.0f - 2.0f * __builtin_amdgcn_rcpf(e + 1.0f);
}

// ---------------- weight prep: fp32 [K][N] -> bf16 A-fragment order ----------------
__global__ void prep_kernel(const float* __restrict__ odeW0, const float* __restrict__ odeW1,
                            const float* __restrict__ odeW2, const float* __restrict__ nvpW0,
                            const float* __restrict__ nvpW1, const float* __restrict__ nvpW2,
                            unsigned short* __restrict__ ws) {
  int idx = blockIdx.x * blockDim.x + threadIdx.x;
  if (idx >= WS_ELEMS) return;
  const float* W; int base, K, N, lstride, skip; float scale;
  int f = idx;
  if (f < OW1_OFF)      { W = odeW0; base = OW0_OFF; K = 64;  N = 256; lstride = 16640; skip = 1; scale = TSCL; f -= OW0_OFF; }
  else if (f < OW2_OFF) { W = odeW1; base = OW1_OFF; K = 256; N = 256; lstride = 65536; skip = 0; scale = TSCL; f -= OW1_OFF; }
  else if (f < NW0_OFF) { W = odeW2; base = OW2_OFF; K = 256; N = 64;  lstride = 16384; skip = 0; scale = 1.f; f -= OW2_OFF; }
  else if (f < NW1_OFF) { W = nvpW0; base = NW0_OFF; K = 32;  N = 256; lstride = 8192;  skip = 0; scale = 1.f; f -= NW0_OFF; }
  else if (f < NW2_OFF) { W = nvpW1; base = NW1_OFF; K = 256; N = 256; lstride = 65536; skip = 0; scale = 1.f; f -= NW1_OFF; }
  else                  { W = nvpW2; base = NW2_OFF; K = 256; N = 64;  lstride = 16384; skip = 0; scale = 1.f; f -= NW2_OFF; }
  int per   = K * N;
  int layer = f / per;
  int e     = f - layer * per;
  int j  = e & 7;
  int l  = (e >> 3) & 63;
  int t  = e >> 9;                 // nt*KS + ks
  int KS = K >> 5; if (KS < 1) KS = 1;
  int ks = t % KS;
  int nt = t / KS;
  int n = nt * 16 + (l & 15);
  int k = ks * 32 + ((l >> 4) << 3) + j;
  ws[base + layer * per + e] = f2bfu_rne(scale * W[layer * lstride + (k + skip) * N + n]);
}

// store 4 consecutive n of batch-row m as bf16 into [m][256], swz (m&15)<<4
__device__ __forceinline__ void st_h(char* dst, int m, int n0, float a, float b, float c, float d) {
  int off = (m * 512 + n0 * 2) ^ ((m & 15) << 4);
  *reinterpret_cast<unsigned long long*>(dst + off) = pack4bf(a, b, c, d);
}

// ---------------- fused flow kernel: 512 blocks x 512 threads, 64 rows/block ----------------
__global__ void
__launch_bounds__(512)
flow_kernel(const float* __restrict__ xin,
            const float* __restrict__ nvp_b0, const float* __restrict__ nvp_b1,
            const float* __restrict__ nvp_b2,
            const float* __restrict__ odeW0_full,
            const float* __restrict__ ode_b0, const float* __restrict__ ode_b1,
            const float* __restrict__ ode_b2,
            const float* __restrict__ bn1m, const float* __restrict__ bn1v,
            const float* __restrict__ bn1g, const float* __restrict__ bn1b,
            const float* __restrict__ bn2m, const float* __restrict__ bn2v,
            const float* __restrict__ bn2g, const float* __restrict__ bn2b,
            const unsigned short* __restrict__ ws,
            float* __restrict__ out) {
  __shared__ __align__(16) char smem[LDS_SIZE];
  char*  h1   = smem + H1_OFF;
  char*  h2   = smem + H2_OFF;
  char*  yinb = smem + YIN_OFF;
  char*  shfb = smem + H1_OFF;       // alias: shf [64][32]bf16 in dead h1 space (after B3)
  float* pars = reinterpret_cast<float*>(smem + PARS_OFF);

  const int tid  = threadIdx.x;
  const int lane = tid & 63;
  const int w    = tid >> 6;        // wave 0..7
  const int l15  = lane & 15;
  const int g    = lane >> 4;
  const int wn   = w & 3;           // y/G3 dim-slice (16 of 64)
  const int wm   = w >> 2;          // y/G3 row-half (32 of 64)
  const int nb   = w * 32;          // G1/G2 n-slice base (32 of 256)
  const int row0 = blockIdx.x * 64;
  const int d0   = wn * 16 + g * 4; // this thread's dim base
  const float dtv = 1.0f / NSTEP;

  float y[8];   // y[mt*4+p] at local row (wm*32 + mt*16 + l15), dim (d0+p)
  #pragma unroll
  for (int mt = 0; mt < 2; ++mt) {
    int m = wm * 32 + mt * 16 + l15;
    floatx4 v = *reinterpret_cast<const floatx4*>(xin + (row0 + m) * 64 + d0);
    y[mt * 4 + 0] = v[0]; y[mt * 4 + 1] = v[1]; y[mt * 4 + 2] = v[2]; y[mt * 4 + 3] = v[3];
  }

  short8 aw0[2][2];   // W0 slice: [nt][ks] (NVP: ks=0 only)
  short8 aw1h[2][2];  // W1 slice head: [nt][ks0..1] (regs; ks2..7 from L2 per eval)
  short8 aw2[8];      // W2 slice: n-slice 16 (wn), 8 ks

  for (int l = 0; l < LNUM; ++l) {
    const short8* w1nvp = reinterpret_cast<const short8*>(ws + NW1_OFF + l * 65536);
    const short8* w1ode = reinterpret_cast<const short8*>(ws + OW1_OFF + l * 65536);

    __syncthreads();                       // B0: prev-layer LDS readers done
    #pragma unroll
    for (int mt = 0; mt < 2; ++mt) {       // stash x halves into yin
      int m = wm * 32 + mt * 16 + l15;
      if (wn >= 2) {                       // x0 (dims 32..63) -> low half-row
        int off = (m * 128 + (d0 - 32) * 2) ^ ((m & 7) << 4);
        *reinterpret_cast<unsigned long long*>(yinb + off) =
            pack4bf(y[mt * 4 + 0], y[mt * 4 + 1], y[mt * 4 + 2], y[mt * 4 + 3]);
      } else {                             // x1 (dims 0..31) -> high half-row
        int off = (m * 128 + 64 + d0 * 2) ^ ((m & 7) << 4);
        *reinterpret_cast<unsigned long long*>(yinb + off) =
            pack4bf(y[mt * 4 + 0], y[mt * 4 + 1], y[mt * 4 + 2], y[mt * 4 + 3]);
      }
    }
    for (int i = tid; i < 576; i += 512) { // NVP biases
      float v;
      if (i < 256)      v = nvp_b0[l * 256 + i];
      else if (i < 512) v = nvp_b1[l * 256 + i - 256];
      else              v = nvp_b2[l * 64 + i - 512];
      pars[i] = v;
    }
    {                                      // NVP W0 + W1-head + W2 slices -> regs
      const short8* p0 = reinterpret_cast<const short8*>(ws + NW0_OFF + l * 8192);
      const short8* p2 = reinterpret_cast<const short8*>(ws + NW2_OFF + l * 16384);
      aw0[0][0] = p0[(w * 2 + 0) * 64 + lane];
      aw0[1][0] = p0[(w * 2 + 1) * 64 + lane];
      #pragma unroll
      for (int nt = 0; nt < 2; ++nt)
        #pragma unroll
        for (int ks = 0; ks < 2; ++ks) aw1h[nt][ks] = w1nvp[((w * 2 + nt) * 8 + ks) * 64 + lane];
      #pragma unroll
      for (int ks = 0; ks < 8; ++ks) aw2[ks] = p2[(wn * 8 + ks) * 64 + lane];
    }
    __syncthreads();                       // B1

    // ---- NVP G1: h1 = relu(x0 @ W0n + b0n), K=32, bias in C-operand ----
    #pragma unroll
    for (int mh = 0; mh < 2; ++mh) {
      floatx4 acc[2][2];
      #pragma unroll
      for (int nt = 0; nt < 2; ++nt) {
        floatx4 bb = *reinterpret_cast<const floatx4*>(pars + nb + nt * 16 + g * 4);
        acc[nt][0] = bb; acc[nt][1] = bb;
      }
      short8 B[2];
      #pragma unroll
      for (int mt = 0; mt < 2; ++mt) {
        int m = mh * 32 + mt * 16 + l15;
        int off = (m * 128 + g * 16) ^ ((m & 7) << 4);
        B[mt] = *reinterpret_cast<const short8*>(yinb + off);
      }
      #pragma unroll
      for (int nt = 0; nt < 2; ++nt)
        #pragma unroll
        for (int mt = 0; mt < 2; ++mt) acc[nt][mt] = MF(aw0[nt][0], B[mt], acc[nt][mt]);
      #pragma unroll
      for (int nt = 0; nt < 2; ++nt) {
        int nbase = nb + nt * 16 + g * 4;
        #pragma unroll
        for (int mt = 0; mt < 2; ++mt) {
          int m = mh * 32 + mt * 16 + l15;
          st_h(h1, m, nbase,
               fmaxf(acc[nt][mt][0], 0.f), fmaxf(acc[nt][mt][1], 0.f),
               fmaxf(acc[nt][mt][2], 0.f), fmaxf(acc[nt][mt][3], 0.f));
        }
      }
    }
    __syncthreads();                       // B2

    // ---- NVP G2: h2 = relu(h1 @ W1n + b1n), bias in C ----
    #pragma unroll
    for (int mh = 0; mh < 2; ++mh) {
      floatx4 acc[2][2];
      #pragma unroll
      for (int nt = 0; nt < 2; ++nt) {
        floatx4 bb = *reinterpret_cast<const floatx4*>(pars + 256 + nb + nt * 16 + g * 4);
        acc[nt][0] = bb; acc[nt][1] = bb;
      }
      #pragma unroll
      for (int ks = 0; ks < 8; ++ks) {
        short8 A[2], B[2];
        if (ks < 2) {
          A[0] = aw1h[0][ks]; A[1] = aw1h[1][ks];
        } else {
          A[0] = w1nvp[((w * 2 + 0) * 8 + ks) * 64 + lane];
          A[1] = w1nvp[((w * 2 + 1) * 8 + ks) * 64 + lane];
        }
        #pragma unroll
        for (int mt = 0; mt < 2; ++mt) {
          int m = mh * 32 + mt * 16 + l15;
          int off = (m * 512 + (ks * 32 + g * 8) * 2) ^ ((m & 15) << 4);
          B[mt] = *reinterpret_cast<const short8*>(h1 + off);
        }
        #pragma unroll
        for (int nt = 0; nt < 2; ++nt)
          #pragma unroll
          for (int mt = 0; mt < 2; ++mt) acc[nt][mt] = MF(A[nt], B[mt], acc[nt][mt]);
      }
      #pragma unroll
      for (int nt = 0; nt < 2; ++nt) {
        int nbase = nb + nt * 16 + g * 4;
        #pragma unroll
        for (int mt = 0; mt < 2; ++mt) {
          int m = mh * 32 + mt * 16 + l15;
          st_h(h2, m, nbase,
               fmaxf(acc[nt][mt][0], 0.f), fmaxf(acc[nt][mt][1], 0.f),
               fmaxf(acc[nt][mt][2], 0.f), fmaxf(acc[nt][mt][3], 0.f));
        }
      }
    }
    __syncthreads();                       // B3: G2 h1 reads done, h2 ready

    // ---- NVP G3: a3 = h2 @ W2n + b2n, bias in C ----
    floatx4 a3[2];
    {
      floatx4 b2v = *reinterpret_cast<const floatx4*>(pars + 512 + d0);
      a3[0] = b2v; a3[1] = b2v;
    }
    #pragma unroll
    for (int ks = 0; ks < 8; ++ks) {
      #pragma unroll
      for (int mt = 0; mt < 2; ++mt) {
        int m = wm * 32 + mt * 16 + l15;
        int off = (m * 512 + (ks * 32 + g * 8) * 2) ^ ((m & 15) << 4);
        short8 B = *reinterpret_cast<const short8*>(h2 + off);
        a3[mt] = MF(aw2[ks], B, a3[mt]);
      }
    }

    if (wn < 2) {                          // shift (dims 0..31) bf16 -> shf (h1 alias; safe after B3)
      #pragma unroll
      for (int mt = 0; mt < 2; ++mt) {
        int m = wm * 32 + mt * 16 + l15;
        int off = (m * 64 + d0 * 2) ^ ((m & 3) << 4);
        *reinterpret_cast<unsigned long long*>(shfb + off) =
            pack4bf(a3[mt][0], a3[mt][1], a3[mt][2], a3[mt][3]);
      }
    }
    __syncthreads();                       // B5

    // ---- recombine + BN1 ----
    #pragma unroll
    for (int mt = 0; mt < 2; ++mt) {
      int m = wm * 32 + mt * 16 + l15;
      if (wn < 2) {                        // new y[d<32] = x0[d] (pass-through from yin low)
        int off = (m * 128 + d0 * 2) ^ ((m & 7) << 4);
        unsigned long long u = *reinterpret_cast<const unsigned long long*>(yinb + off);
        y[mt * 4 + 0] = bfu2f((unsigned short)(u));
        y[mt * 4 + 1] = bfu2f((unsigned short)(u >> 16));
        y[mt * 4 + 2] = bfu2f((unsigned short)(u >> 32));
        y[mt * 4 + 3] = bfu2f((unsigned short)(u >> 48));
      } else {                             // new y[32+j] = x1[j]*exp(ls[j]) + shift[j]
        int offx = (m * 128 + 64 + (d0 - 32) * 2) ^ ((m & 7) << 4);
        unsigned long long ux = *reinterpret_cast<const unsigned long long*>(yinb + offx);
        int offs = (m * 64 + (d0 - 32) * 2) ^ ((m & 3) << 4);
        unsigned long long us = *reinterpret_cast<const unsigned long long*>(shfb + offs);
        y[mt * 4 + 0] = bfu2f((unsigned short)(ux)) * __expf(a3[mt][0]) + bfu2f((unsigned short)(us));
        y[mt * 4 + 1] = bfu2f((unsigned short)(ux >> 16)) * __expf(a3[mt][1]) + bfu2f((unsigned short)(us >> 16));
        y[mt * 4 + 2] = bfu2f((unsigned short)(ux >> 32)) * __expf(a3[mt][2]) + bfu2f((unsigned short)(us >> 32));
        y[mt * 4 + 3] = bfu2f((unsigned short)(ux >> 48)) * __expf(a3[mt][3]) + bfu2f((unsigned short)(us >> 48));
      }
    }
    {
      floatx4 mm = *reinterpret_cast<const floatx4*>(bn1m + l * 64 + d0);
      floatx4 vv = *reinterpret_cast<const floatx4*>(bn1v + l * 64 + d0);
      floatx4 gg = *reinterpret_cast<const floatx4*>(bn1g + l * 64 + d0);
      floatx4 be = *reinterpret_cast<const floatx4*>(bn1b + l * 64 + d0);
      float sc[4];
      #pragma unroll
      for (int p = 0; p < 4; ++p) sc[p] = sqrtf(vv[p] + EPSV) / gg[p];
      #pragma unroll
      for (int mt = 0; mt < 2; ++mt)
        #pragma unroll
        for (int p = 0; p < 4; ++p)
          y[mt * 4 + p] = (y[mt * 4 + p] - be[p]) * sc[p] + mm[p];
    }

    for (int i = tid; i < 832; i += 512) { // ODE biases + t-row (b0/b1/trow PRE-SCALED 2log2e)
      float v;
      if (i < 256)      v = TSCL * ode_b0[l * 256 + i];
      else if (i < 512) v = TSCL * ode_b1[l * 256 + i - 256];
      else if (i < 576) v = ode_b2[l * 64 + i - 512];
      else              v = TSCL * odeW0_full[l * 16640 + i - 576];
      pars[i] = v;
    }
    {                                      // ODE W0 + W1-head + W2 slices -> regs
      const short8* p0 = reinterpret_cast<const short8*>(ws + OW0_OFF + l * 16384);
      const short8* p2 = reinterpret_cast<const short8*>(ws + OW2_OFF + l * 16384);
      #pragma unroll
      for (int nt = 0; nt < 2; ++nt)
        #pragma unroll
        for (int ks = 0; ks < 2; ++ks) aw0[nt][ks] = p0[((w * 2 + nt) * 2 + ks) * 64 + lane];
      #pragma unroll
      for (int nt = 0; nt < 2; ++nt)
        #pragma unroll
        for (int ks = 0; ks < 2; ++ks) aw1h[nt][ks] = w1ode[((w * 2 + nt) * 8 + ks) * 64 + lane];
      #pragma unroll
      for (int ks = 0; ks < 8; ++ks) aw2[ks] = p2[(wn * 8 + ks) * 64 + lane];
    }
    __syncthreads();                       // B6

    // ================= FFJORD: 8 RK4 steps, 3 barriers/eval =================
    float ka[8], kc[8];
    for (int s = 0; s < NSTEP; ++s) {
      float t0 = (float)s * dtv;
      for (int stg = 0; stg < 4; ++stg) {
        float cadd = (stg == 0) ? 0.0f : ((stg == 3) ? dtv : 0.5f * dtv);
        float tcur = t0 + cadd;
        #pragma unroll
        for (int mt = 0; mt < 2; ++mt) {   // yin = y (+ cadd*k_prev), bf16 [64][64]
          int m = wm * 32 + mt * 16 + l15;
          float v0, v1, v2, v3;
          if (stg == 0) {
            v0 = y[mt * 4 + 0]; v1 = y[mt * 4 + 1]; v2 = y[mt * 4 + 2]; v3 = y[mt * 4 + 3];
          } else {
            v0 = fmaf(cadd, kc[mt * 4 + 0], y[mt * 4 + 0]);
            v1 = fmaf(cadd, kc[mt * 4 + 1], y[mt * 4 + 1]);
            v2 = fmaf(cadd, kc[mt * 4 + 2], y[mt * 4 + 2]);
            v3 = fmaf(cadd, kc[mt * 4 + 3], y[mt * 4 + 3]);
          }
          int off = (m * 128 + d0 * 2) ^ ((m & 7) << 4);
          *reinterpret_cast<unsigned long long*>(yinb + off) = pack4bf(v0, v1, v2, v3);
        }
        __syncthreads();                   // (a)

        // G1: h1 = tanh2(yin @ W0o + c), c = b0o + tcur*w0row0 in C-operand
        #pragma unroll
        for (int mh = 0; mh < 2; ++mh) {
          floatx4 acc[2][2];
          #pragma unroll
          for (int nt = 0; nt < 2; ++nt) {
            int nbase = nb + nt * 16 + g * 4;
            floatx4 bb = *reinterpret_cast<const floatx4*>(pars + nbase);
            floatx4 w0 = *reinterpret_cast<const floatx4*>(pars + 576 + nbase);
            floatx4 c;
            c[0] = fmaf(tcur, w0[0], bb[0]); c[1] = fmaf(tcur, w0[1], bb[1]);
            c[2] = fmaf(tcur, w0[2], bb[2]); c[3] = fmaf(tcur, w0[3], bb[3]);
            acc[nt][0] = c; acc[nt][1] = c;
          }
          #pragma unroll
          for (int ks = 0; ks < 2; ++ks) {
            short8 B[2];
            #pragma unroll
            for (int mt = 0; mt < 2; ++mt) {
              int m = mh * 32 + mt * 16 + l15;
              int off = (m * 128 + (ks * 32 + g * 8) * 2) ^ ((m & 7) << 4);
              B[mt] = *reinterpret_cast<const short8*>(yinb + off);
            }
            #pragma unroll
            for (int nt = 0; nt < 2; ++nt)
              #pragma unroll
              for (int mt = 0; mt < 2; ++mt) acc[nt][mt] = MF(aw0[nt][ks], B[mt], acc[nt][mt]);
          }
          #pragma unroll
          for (int nt = 0; nt < 2; ++nt) {
            int nbase = nb + nt * 16 + g * 4;
            #pragma unroll
            for (int mt = 0; mt < 2; ++mt) {
              int m = mh * 32 + mt * 16 + l15;
              st_h(h1, m, nbase,
                   tanh_fast2(acc[nt][mt][0]), tanh_fast2(acc[nt][mt][1]),
                   tanh_fast2(acc[nt][mt][2]), tanh_fast2(acc[nt][mt][3]));
            }
          }
        }
        __syncthreads();                   // (b)

        // G2: h2 = tanh2(h1 @ W1o + b1o), bias in C
        #pragma unroll
        for (int mh = 0; mh < 2; ++mh) {
          floatx4 acc[2][2];
          #pragma unroll
          for (int nt = 0; nt < 2; ++nt) {
            floatx4 bb = *reinterpret_cast<const floatx4*>(pars + 256 + nb + nt * 16 + g * 4);
            acc[nt][0] = bb; acc[nt][1] = bb;
          }
          #pragma unroll
          for (int ks = 0; ks < 8; ++ks) {
            short8 A[2], B[2];
            if (ks < 2) {
              A[0] = aw1h[0][ks]; A[1] = aw1h[1][ks];
            } else {
              A[0] = w1ode[((w * 2 + 0) * 8 + ks) * 64 + lane];
              A[1] = w1ode[((w * 2 + 1) * 8 + ks) * 64 + lane];
            }
            #pragma unroll
            for (int mt = 0; mt < 2; ++mt) {
              int m = mh * 32 + mt * 16 + l15;
              int off = (m * 512 + (ks * 32 + g * 8) * 2) ^ ((m & 15) << 4);
              B[mt] = *reinterpret_cast<const short8*>(h1 + off);
            }
            #pragma unroll
            for (int nt = 0; nt < 2; ++nt)
              #pragma unroll
              for (int mt = 0; mt < 2; ++mt) acc[nt][mt] = MF(A[nt], B[mt], acc[nt][mt]);
          }
          #pragma unroll
          for (int nt = 0; nt < 2; ++nt) {
            int nbase = nb + nt * 16 + g * 4;
            #pragma unroll
            for (int mt = 0; mt < 2; ++mt) {
              int m = mh * 32 + mt * 16 + l15;
              st_h(h2, m, nbase,
                   tanh_fast2(acc[nt][mt][0]), tanh_fast2(acc[nt][mt][1]),
                   tanh_fast2(acc[nt][mt][2]), tanh_fast2(acc[nt][mt][3]));
            }
          }
        }
        __syncthreads();                   // (d')

        // G3: k = h2 @ W2o + b2o, bias in C
        {
          floatx4 a2[2];
          {
            floatx4 b2v = *reinterpret_cast<const floatx4*>(pars + 512 + d0);
            a2[0] = b2v; a2[1] = b2v;
          }
          #pragma unroll
          for (int ks = 0; ks < 8; ++ks) {
            #pragma unroll
            for (int mt = 0; mt < 2; ++mt) {
              int m = wm * 32 + mt * 16 + l15;
              int off = (m * 512 + (ks * 32 + g * 8) * 2) ^ ((m & 15) << 4);
              short8 B = *reinterpret_cast<const short8*>(h2 + off);
              a2[mt] = MF(aw2[ks], B, a2[mt]);
            }
          }
          #pragma unroll
          for (int mt = 0; mt < 2; ++mt)
            #pragma unroll
            for (int p = 0; p < 4; ++p)
              kc[mt * 4 + p] = a2[mt][p];
        }
        if (stg == 0) {
          #pragma unroll
          for (int i = 0; i < 8; ++i) ka[i] = kc[i];
        } else if (stg == 3) {
          #pragma unroll
          for (int i = 0; i < 8; ++i) ka[i] += kc[i];
        } else {
          #pragma unroll
          for (int i = 0; i < 8; ++i) ka[i] += 2.0f * kc[i];
        }
      }
      #pragma unroll
      for (int i = 0; i < 8; ++i) y[i] += (dtv / 6.0f) * ka[i];
    }

    {                                      // BN2
      floatx4 mm = *reinterpret_cast<const floatx4*>(bn2m + l * 64 + d0);
      floatx4 vv = *reinterpret_cast<const floatx4*>(bn2v + l * 64 + d0);
      floatx4 gg = *reinterpret_cast<const floatx4*>(bn2g + l * 64 + d0);
      floatx4 be = *reinterpret_cast<const floatx4*>(bn2b + l * 64 + d0);
      float sc[4];
      #pragma unroll
      for (int p = 0; p < 4; ++p) sc[p] = sqrtf(vv[p] + EPSV) / gg[p];
      #pragma unroll
      for (int mt = 0; mt < 2; ++mt)
        #pragma unroll
        for (int p = 0; p < 4; ++p)
          y[mt * 4 + p] = (y[mt * 4 + p] - be[p]) * sc[p] + mm[p];
    }
  }

  #pragma unroll
  for (int mt = 0; mt < 2; ++mt) {
    int m = wm * 32 + mt * 16 + l15;
    floatx4 v = {y[mt * 4 + 0], y[mt * 4 + 1], y[mt * 4 + 2], y[mt * 4 + 3]};
    *reinterpret_cast<floatx4*>(out + (row0 + m) * 64 + d0) = v;
  }
}

extern "C" void kernel_launch(void* const* d_in, const int* in_sizes, int n_in,
                              void* d_out, int out_size, void* d_ws, size_t ws_size,
                              hipStream_t stream) {
  const float* x      = (const float*)d_in[0];
  const float* nvpW0  = (const float*)d_in[2];
  const float* nvp_b0 = (const float*)d_in[3];
  const float* nvpW1  = (const float*)d_in[4];
  const float* nvp_b1 = (const float*)d_in[5];
  const float* nvpW2  = (const float*)d_in[6];
  const float* nvp_b2 = (const float*)d_in[7];
  const float* odeW0  = (const float*)d_in[8];
  const float* ode_b0 = (const float*)d_in[9];
  const float* odeW1  = (const float*)d_in[10];
  const float* ode_b1 = (const float*)d_in[11];
  const float* odeW2  = (const float*)d_in[12];
  const float* ode_b2 = (const float*)d_in[13];
  const float* bn1m   = (const float*)d_in[14];
  const float* bn1v   = (const float*)d_in[15];
  const float* bn1g   = (const float*)d_in[16];
  const float* bn1b   = (const float*)d_in[17];
  const float* bn2m   = (const float*)d_in[18];
  const float* bn2v   = (const float*)d_in[19];
  const float* bn2g   = (const float*)d_in[20];
  const float* bn2b   = (const float*)d_in[21];
  unsigned short* ws  = (unsigned short*)d_ws;
  float* out          = (float*)d_out;

  int pblocks = (WS_ELEMS + 255) / 256;
  prep_kernel<<<pblocks, 256, 0, stream>>>(odeW0, odeW1, odeW2, nvpW0, nvpW1, nvpW2, ws);
  flow_kernel<<<512, 512, 0, stream>>>(x, nvp_b0, nvp_b1, nvp_b2, odeW0,
                                       ode_b0, ode_b1, ode_b2,
                                       bn1m, bn1v, bn1g, bn1b,
                                       bn2m, bn2v, bn2g, bn2b,
                                       ws, out);
}

// Round 19
// 1083.554 us; speedup vs baseline: 1.2768x; 1.2768x over previous
//
#include <hip/hip_runtime.h>
#include <hip/hip_bf16.h>

// StackedFlow v17 = r18 with ONE change: tanh_fast2 uses __builtin_amdgcn_exp2f
// (raw v_exp_f32). r18's regression (1136->1384, VALU 58.6->62%) was exp2f() mapping
// to OCML's PRECISE __ocml_exp2_f32 (range checks, several extra VALU) instead of the
// fast native exp — the prefold itself is sound. v17 = v14 structure + 2log2e prefold
// + native exp2: per-tanh = 1 trans op (v14: mul + trans). Predict 1080-1120us.

#define LNUM   4
#define NSTEP  8
#define EPSV   1e-3f
#define TSCL   2.8853900817779268f   // 2*log2(e)

typedef __attribute__((ext_vector_type(8))) short  short8;
typedef __attribute__((ext_vector_type(4))) float  floatx4;

#define MF(a, b, c) __builtin_amdgcn_mfma_f32_16x16x32_bf16((a), (b), (c), 0, 0, 0)

// d_ws layout (bf16 element offsets), per-GEMM fragment arrays [layer][nt*KS+ks][lane][8]
#define OW0_OFF 0        // ode W0 rows 1..64  (64 x 256)  PRE-SCALED x 2log2e
#define OW1_OFF 65536    // ode W1            (256 x 256)  PRE-SCALED x 2log2e
#define OW2_OFF 327680   // ode W2            (256 x 64)
#define NW0_OFF 393216   // nvp W0            (32 x 256)
#define NW1_OFF 425984   // nvp W1            (256 x 256)
#define NW2_OFF 688128   // nvp W2            (256 x 64)
#define WS_ELEMS 753664

// LDS byte offsets (64-row tile, 75.3KB)
#define H1_OFF   0        // 32K bf16 [64][256] RS=512 swz((m&15)<<4); first 4K aliases shf
#define H2_OFF   32768    // 32K bf16 [64][256] RS=512 swz((m&15)<<4)
#define YIN_OFF  65536    // 8K  bf16 [64][64]  RS=128 swz((m&7)<<4); NVP: x0 lo, x1 hi half-row
#define PARS_OFF 73728    // 3328B: b0 | b1(+256) | b2(+512) | w0row0(+576)
#define LDS_SIZE 77056

__device__ __forceinline__ unsigned short f2bfu_rne(float f) {
  unsigned int u = __float_as_uint(f);
  return (unsigned short)((u + 0x7FFFu + ((u >> 16) & 1u)) >> 16);  // RNE (prep only)
}

__device__ __forceinline__ unsigned long long pack4bf(float a, float b, float c, float d) {
  __hip_bfloat162 lo = __float22bfloat162_rn(make_float2(a, b));
  __hip_bfloat162 hi = __float22bfloat162_rn(make_float2(c, d));
  unsigned int ul, uh;
  __builtin_memcpy(&ul, &lo, 4);
  __builtin_memcpy(&uh, &hi, 4);
  return (unsigned long long)ul | ((unsigned long long)uh << 32);
}

__device__ __forceinline__ float bfu2f(unsigned short u) {
  return __uint_as_float((unsigned int)u << 16);
}

// input v is ALREADY 2*log2(e) x the mathematical pre-activation -> e^{2x} = 2^v
__device__ __forceinline__ float tanh_fast2(float v) {
  float e = __builtin_amdgcn_exp2f(v);     // raw v_exp_f32, no OCML wrapper
  return 1.0f - 2.0f * __builtin_amdgcn_rcpf(e + 1.0f);
}

// ---------------- weight prep: fp32 [K][N] -> bf16 A-fragment order ----------------
__global__ void prep_kernel(const float* __restrict__ odeW0, const float* __restrict__ odeW1,
                            const float* __restrict__ odeW2, const float* __restrict__ nvpW0,
                            const float* __restrict__ nvpW1, const float* __restrict__ nvpW2,
                            unsigned short* __restrict__ ws) {
  int idx = blockIdx.x * blockDim.x + threadIdx.x;
  if (idx >= WS_ELEMS) return;
  const float* W; int base, K, N, lstride, skip; float scale;
  int f = idx;
  if (f < OW1_OFF)      { W = odeW0; base = OW0_OFF; K = 64;  N = 256; lstride = 16640; skip = 1; scale = TSCL; f -= OW0_OFF; }
  else if (f < OW2_OFF) { W = odeW1; base = OW1_OFF; K = 256; N = 256; lstride = 65536; skip = 0; scale = TSCL; f -= OW1_OFF; }
  else if (f < NW0_OFF) { W = odeW2; base = OW2_OFF; K = 256; N = 64;  lstride = 16384; skip = 0; scale = 1.f; f -= OW2_OFF; }
  else if (f < NW1_OFF) { W = nvpW0; base = NW0_OFF; K = 32;  N = 256; lstride = 8192;  skip = 0; scale = 1.f; f -= NW0_OFF; }
  else if (f < NW2_OFF) { W = nvpW1; base = NW1_OFF; K = 256; N = 256; lstride = 65536; skip = 0; scale = 1.f; f -= NW1_OFF; }
  else                  { W = nvpW2; base = NW2_OFF; K = 256; N = 64;  lstride = 16384; skip = 0; scale = 1.f; f -= NW2_OFF; }
  int per   = K * N;
  int layer = f / per;
  int e     = f - layer * per;
  int j  = e & 7;
  int l  = (e >> 3) & 63;
  int t  = e >> 9;                 // nt*KS + ks
  int KS = K >> 5; if (KS < 1) KS = 1;
  int ks = t % KS;
  int nt = t / KS;
  int n = nt * 16 + (l & 15);
  int k = ks * 32 + ((l >> 4) << 3) + j;
  ws[base + layer * per + e] = f2bfu_rne(scale * W[layer * lstride + (k + skip) * N + n]);
}

// store 4 consecutive n of batch-row m as bf16 into [m][256], swz (m&15)<<4
__device__ __forceinline__ void st_h(char* dst, int m, int n0, float a, float b, float c, float d) {
  int off = (m * 512 + n0 * 2) ^ ((m & 15) << 4);
  *reinterpret_cast<unsigned long long*>(dst + off) = pack4bf(a, b, c, d);
}

// ---------------- fused flow kernel: 512 blocks x 512 threads, 64 rows/block ----------------
__global__ void
__launch_bounds__(512)
flow_kernel(const float* __restrict__ xin,
            const float* __restrict__ nvp_b0, const float* __restrict__ nvp_b1,
            const float* __restrict__ nvp_b2,
            const float* __restrict__ odeW0_full,
            const float* __restrict__ ode_b0, const float* __restrict__ ode_b1,
            const float* __restrict__ ode_b2,
            const float* __restrict__ bn1m, const float* __restrict__ bn1v,
            const float* __restrict__ bn1g, const float* __restrict__ bn1b,
            const float* __restrict__ bn2m, const float* __restrict__ bn2v,
            const float* __restrict__ bn2g, const float* __restrict__ bn2b,
            const unsigned short* __restrict__ ws,
            float* __restrict__ out) {
  __shared__ __align__(16) char smem[LDS_SIZE];
  char*  h1   = smem + H1_OFF;
  char*  h2   = smem + H2_OFF;
  char*  yinb = smem + YIN_OFF;
  char*  shfb = smem + H1_OFF;       // alias: shf [64][32]bf16 in dead h1 space (after B3)
  float* pars = reinterpret_cast<float*>(smem + PARS_OFF);

  const int tid  = threadIdx.x;
  const int lane = tid & 63;
  const int w    = tid >> 6;        // wave 0..7
  const int l15  = lane & 15;
  const int g    = lane >> 4;
  const int wn   = w & 3;           // y/G3 dim-slice (16 of 64)
  const int wm   = w >> 2;          // y/G3 row-half (32 of 64)
  const int nb   = w * 32;          // G1/G2 n-slice base (32 of 256)
  const int row0 = blockIdx.x * 64;
  const int d0   = wn * 16 + g * 4; // this thread's dim base
  const float dtv = 1.0f / NSTEP;

  float y[8];   // y[mt*4+p] at local row (wm*32 + mt*16 + l15), dim (d0+p)
  #pragma unroll
  for (int mt = 0; mt < 2; ++mt) {
    int m = wm * 32 + mt * 16 + l15;
    floatx4 v = *reinterpret_cast<const floatx4*>(xin + (row0 + m) * 64 + d0);
    y[mt * 4 + 0] = v[0]; y[mt * 4 + 1] = v[1]; y[mt * 4 + 2] = v[2]; y[mt * 4 + 3] = v[3];
  }

  short8 aw0[2][2];   // W0 slice: [nt][ks] (NVP: ks=0 only)
  short8 aw1h[2][2];  // W1 slice head: [nt][ks0..1] (regs; ks2..7 from L2 per eval)
  short8 aw2[8];      // W2 slice: n-slice 16 (wn), 8 ks

  for (int l = 0; l < LNUM; ++l) {
    const short8* w1nvp = reinterpret_cast<const short8*>(ws + NW1_OFF + l * 65536);
    const short8* w1ode = reinterpret_cast<const short8*>(ws + OW1_OFF + l * 65536);

    __syncthreads();                       // B0: prev-layer LDS readers done
    #pragma unroll
    for (int mt = 0; mt < 2; ++mt) {       // stash x halves into yin
      int m = wm * 32 + mt * 16 + l15;
      if (wn >= 2) {                       // x0 (dims 32..63) -> low half-row
        int off = (m * 128 + (d0 - 32) * 2) ^ ((m & 7) << 4);
        *reinterpret_cast<unsigned long long*>(yinb + off) =
            pack4bf(y[mt * 4 + 0], y[mt * 4 + 1], y[mt * 4 + 2], y[mt * 4 + 3]);
      } else {                             // x1 (dims 0..31) -> high half-row
        int off = (m * 128 + 64 + d0 * 2) ^ ((m & 7) << 4);
        *reinterpret_cast<unsigned long long*>(yinb + off) =
            pack4bf(y[mt * 4 + 0], y[mt * 4 + 1], y[mt * 4 + 2], y[mt * 4 + 3]);
      }
    }
    for (int i = tid; i < 576; i += 512) { // NVP biases
      float v;
      if (i < 256)      v = nvp_b0[l * 256 + i];
      else if (i < 512) v = nvp_b1[l * 256 + i - 256];
      else              v = nvp_b2[l * 64 + i - 512];
      pars[i] = v;
    }
    {                                      // NVP W0 + W1-head + W2 slices -> regs
      const short8* p0 = reinterpret_cast<const short8*>(ws + NW0_OFF + l * 8192);
      const short8* p2 = reinterpret_cast<const short8*>(ws + NW2_OFF + l * 16384);
      aw0[0][0] = p0[(w * 2 + 0) * 64 + lane];
      aw0[1][0] = p0[(w * 2 + 1) * 64 + lane];
      #pragma unroll
      for (int nt = 0; nt < 2; ++nt)
        #pragma unroll
        for (int ks = 0; ks < 2; ++ks) aw1h[nt][ks] = w1nvp[((w * 2 + nt) * 8 + ks) * 64 + lane];
      #pragma unroll
      for (int ks = 0; ks < 8; ++ks) aw2[ks] = p2[(wn * 8 + ks) * 64 + lane];
    }
    __syncthreads();                       // B1

    // ---- NVP G1: h1 = relu(x0 @ W0n + b0n), K=32, bias in C-operand ----
    #pragma unroll
    for (int mh = 0; mh < 2; ++mh) {
      floatx4 acc[2][2];
      #pragma unroll
      for (int nt = 0; nt < 2; ++nt) {
        floatx4 bb = *reinterpret_cast<const floatx4*>(pars + nb + nt * 16 + g * 4);
        acc[nt][0] = bb; acc[nt][1] = bb;
      }
      short8 B[2];
      #pragma unroll
      for (int mt = 0; mt < 2; ++mt) {
        int m = mh * 32 + mt * 16 + l15;
        int off = (m * 128 + g * 16) ^ ((m & 7) << 4);
        B[mt] = *reinterpret_cast<const short8*>(yinb + off);
      }
      #pragma unroll
      for (int nt = 0; nt < 2; ++nt)
        #pragma unroll
        for (int mt = 0; mt < 2; ++mt) acc[nt][mt] = MF(aw0[nt][0], B[mt], acc[nt][mt]);
      #pragma unroll
      for (int nt = 0; nt < 2; ++nt) {
        int nbase = nb + nt * 16 + g * 4;
        #pragma unroll
        for (int mt = 0; mt < 2; ++mt) {
          int m = mh * 32 + mt * 16 + l15;
          st_h(h1, m, nbase,
               fmaxf(acc[nt][mt][0], 0.f), fmaxf(acc[nt][mt][1], 0.f),
               fmaxf(acc[nt][mt][2], 0.f), fmaxf(acc[nt][mt][3], 0.f));
        }
      }
    }
    __syncthreads();                       // B2

    // ---- NVP G2: h2 = relu(h1 @ W1n + b1n), bias in C ----
    #pragma unroll
    for (int mh = 0; mh < 2; ++mh) {
      floatx4 acc[2][2];
      #pragma unroll
      for (int nt = 0; nt < 2; ++nt) {
        floatx4 bb = *reinterpret_cast<const floatx4*>(pars + 256 + nb + nt * 16 + g * 4);
        acc[nt][0] = bb; acc[nt][1] = bb;
      }
      #pragma unroll
      for (int ks = 0; ks < 8; ++ks) {
        short8 A[2], B[2];
        if (ks < 2) {
          A[0] = aw1h[0][ks]; A[1] = aw1h[1][ks];
        } else {
          A[0] = w1nvp[((w * 2 + 0) * 8 + ks) * 64 + lane];
          A[1] = w1nvp[((w * 2 + 1) * 8 + ks) * 64 + lane];
        }
        #pragma unroll
        for (int mt = 0; mt < 2; ++mt) {
          int m = mh * 32 + mt * 16 + l15;
          int off = (m * 512 + (ks * 32 + g * 8) * 2) ^ ((m & 15) << 4);
          B[mt] = *reinterpret_cast<const short8*>(h1 + off);
        }
        #pragma unroll
        for (int nt = 0; nt < 2; ++nt)
          #pragma unroll
          for (int mt = 0; mt < 2; ++mt) acc[nt][mt] = MF(A[nt], B[mt], acc[nt][mt]);
      }
      #pragma unroll
      for (int nt = 0; nt < 2; ++nt) {
        int nbase = nb + nt * 16 + g * 4;
        #pragma unroll
        for (int mt = 0; mt < 2; ++mt) {
          int m = mh * 32 + mt * 16 + l15;
          st_h(h2, m, nbase,
               fmaxf(acc[nt][mt][0], 0.f), fmaxf(acc[nt][mt][1], 0.f),
               fmaxf(acc[nt][mt][2], 0.f), fmaxf(acc[nt][mt][3], 0.f));
        }
      }
    }
    __syncthreads();                       // B3: G2 h1 reads done, h2 ready

    // ---- NVP G3: a3 = h2 @ W2n + b2n, bias in C ----
    floatx4 a3[2];
    {
      floatx4 b2v = *reinterpret_cast<const floatx4*>(pars + 512 + d0);
      a3[0] = b2v; a3[1] = b2v;
    }
    #pragma unroll
    for (int ks = 0; ks < 8; ++ks) {
      #pragma unroll
      for (int mt = 0; mt < 2; ++mt) {
        int m = wm * 32 + mt * 16 + l15;
        int off = (m * 512 + (ks * 32 + g * 8) * 2) ^ ((m & 15) << 4);
        short8 B = *reinterpret_cast<const short8*>(h2 + off);
        a3[mt] = MF(aw2[ks], B, a3[mt]);
      }
    }

    if (wn < 2) {                          // shift (dims 0..31) bf16 -> shf (h1 alias; safe after B3)
      #pragma unroll
      for (int mt = 0; mt < 2; ++mt) {
        int m = wm * 32 + mt * 16 + l15;
        int off = (m * 64 + d0 * 2) ^ ((m & 3) << 4);
        *reinterpret_cast<unsigned long long*>(shfb + off) =
            pack4bf(a3[mt][0], a3[mt][1], a3[mt][2], a3[mt][3]);
      }
    }
    __syncthreads();                       // B5

    // ---- recombine + BN1 ----
    #pragma unroll
    for (int mt = 0; mt < 2; ++mt) {
      int m = wm * 32 + mt * 16 + l15;
      if (wn < 2) {                        // new y[d<32] = x0[d] (pass-through from yin low)
        int off = (m * 128 + d0 * 2) ^ ((m & 7) << 4);
        unsigned long long u = *reinterpret_cast<const unsigned long long*>(yinb + off);
        y[mt * 4 + 0] = bfu2f((unsigned short)(u));
        y[mt * 4 + 1] = bfu2f((unsigned short)(u >> 16));
        y[mt * 4 + 2] = bfu2f((unsigned short)(u >> 32));
        y[mt * 4 + 3] = bfu2f((unsigned short)(u >> 48));
      } else {                             // new y[32+j] = x1[j]*exp(ls[j]) + shift[j]
        int offx = (m * 128 + 64 + (d0 - 32) * 2) ^ ((m & 7) << 4);
        unsigned long long ux = *reinterpret_cast<const unsigned long long*>(yinb + offx);
        int offs = (m * 64 + (d0 - 32) * 2) ^ ((m & 3) << 4);
        unsigned long long us = *reinterpret_cast<const unsigned long long*>(shfb + offs);
        y[mt * 4 + 0] = bfu2f((unsigned short)(ux)) * __expf(a3[mt][0]) + bfu2f((unsigned short)(us));
        y[mt * 4 + 1] = bfu2f((unsigned short)(ux >> 16)) * __expf(a3[mt][1]) + bfu2f((unsigned short)(us >> 16));
        y[mt * 4 + 2] = bfu2f((unsigned short)(ux >> 32)) * __expf(a3[mt][2]) + bfu2f((unsigned short)(us >> 32));
        y[mt * 4 + 3] = bfu2f((unsigned short)(ux >> 48)) * __expf(a3[mt][3]) + bfu2f((unsigned short)(us >> 48));
      }
    }
    {
      floatx4 mm = *reinterpret_cast<const floatx4*>(bn1m + l * 64 + d0);
      floatx4 vv = *reinterpret_cast<const floatx4*>(bn1v + l * 64 + d0);
      floatx4 gg = *reinterpret_cast<const floatx4*>(bn1g + l * 64 + d0);
      floatx4 be = *reinterpret_cast<const floatx4*>(bn1b + l * 64 + d0);
      float sc[4];
      #pragma unroll
      for (int p = 0; p < 4; ++p) sc[p] = sqrtf(vv[p] + EPSV) / gg[p];
      #pragma unroll
      for (int mt = 0; mt < 2; ++mt)
        #pragma unroll
        for (int p = 0; p < 4; ++p)
          y[mt * 4 + p] = (y[mt * 4 + p] - be[p]) * sc[p] + mm[p];
    }

    for (int i = tid; i < 832; i += 512) { // ODE biases + t-row (b0/b1/trow PRE-SCALED 2log2e)
      float v;
      if (i < 256)      v = TSCL * ode_b0[l * 256 + i];
      else if (i < 512) v = TSCL * ode_b1[l * 256 + i - 256];
      else if (i < 576) v = ode_b2[l * 64 + i - 512];
      else              v = TSCL * odeW0_full[l * 16640 + i - 576];
      pars[i] = v;
    }
    {                                      // ODE W0 + W1-head + W2 slices -> regs
      const short8* p0 = reinterpret_cast<const short8*>(ws + OW0_OFF + l * 16384);
      const short8* p2 = reinterpret_cast<const short8*>(ws + OW2_OFF + l * 16384);
      #pragma unroll
      for (int nt = 0; nt < 2; ++nt)
        #pragma unroll
        for (int ks = 0; ks < 2; ++ks) aw0[nt][ks] = p0[((w * 2 + nt) * 2 + ks) * 64 + lane];
      #pragma unroll
      for (int nt = 0; nt < 2; ++nt)
        #pragma unroll
        for (int ks = 0; ks < 2; ++ks) aw1h[nt][ks] = w1ode[((w * 2 + nt) * 8 + ks) * 64 + lane];
      #pragma unroll
      for (int ks = 0; ks < 8; ++ks) aw2[ks] = p2[(wn * 8 + ks) * 64 + lane];
    }
    __syncthreads();                       // B6

    // ================= FFJORD: 8 RK4 steps, 3 barriers/eval =================
    float ka[8], kc[8];
    for (int s = 0; s < NSTEP; ++s) {
      float t0 = (float)s * dtv;
      for (int stg = 0; stg < 4; ++stg) {
        float cadd = (stg == 0) ? 0.0f : ((stg == 3) ? dtv : 0.5f * dtv);
        float tcur = t0 + cadd;
        #pragma unroll
        for (int mt = 0; mt < 2; ++mt) {   // yin = y (+ cadd*k_prev), bf16 [64][64]
          int m = wm * 32 + mt * 16 + l15;
          float v0, v1, v2, v3;
          if (stg == 0) {
            v0 = y[mt * 4 + 0]; v1 = y[mt * 4 + 1]; v2 = y[mt * 4 + 2]; v3 = y[mt * 4 + 3];
          } else {
            v0 = fmaf(cadd, kc[mt * 4 + 0], y[mt * 4 + 0]);
            v1 = fmaf(cadd, kc[mt * 4 + 1], y[mt * 4 + 1]);
            v2 = fmaf(cadd, kc[mt * 4 + 2], y[mt * 4 + 2]);
            v3 = fmaf(cadd, kc[mt * 4 + 3], y[mt * 4 + 3]);
          }
          int off = (m * 128 + d0 * 2) ^ ((m & 7) << 4);
          *reinterpret_cast<unsigned long long*>(yinb + off) = pack4bf(v0, v1, v2, v3);
        }
        __syncthreads();                   // (a)

        // G1: h1 = tanh2(yin @ W0o + c), c = b0o + tcur*w0row0 in C-operand
        #pragma unroll
        for (int mh = 0; mh < 2; ++mh) {
          floatx4 acc[2][2];
          #pragma unroll
          for (int nt = 0; nt < 2; ++nt) {
            int nbase = nb + nt * 16 + g * 4;
            floatx4 bb = *reinterpret_cast<const floatx4*>(pars + nbase);
            floatx4 w0 = *reinterpret_cast<const floatx4*>(pars + 576 + nbase);
            floatx4 c;
            c[0] = fmaf(tcur, w0[0], bb[0]); c[1] = fmaf(tcur, w0[1], bb[1]);
            c[2] = fmaf(tcur, w0[2], bb[2]); c[3] = fmaf(tcur, w0[3], bb[3]);
            acc[nt][0] = c; acc[nt][1] = c;
          }
          #pragma unroll
          for (int ks = 0; ks < 2; ++ks) {
            short8 B[2];
            #pragma unroll
            for (int mt = 0; mt < 2; ++mt) {
              int m = mh * 32 + mt * 16 + l15;
              int off = (m * 128 + (ks * 32 + g * 8) * 2) ^ ((m & 7) << 4);
              B[mt] = *reinterpret_cast<const short8*>(yinb + off);
            }
            #pragma unroll
            for (int nt = 0; nt < 2; ++nt)
              #pragma unroll
              for (int mt = 0; mt < 2; ++mt) acc[nt][mt] = MF(aw0[nt][ks], B[mt], acc[nt][mt]);
          }
          #pragma unroll
          for (int nt = 0; nt < 2; ++nt) {
            int nbase = nb + nt * 16 + g * 4;
            #pragma unroll
            for (int mt = 0; mt < 2; ++mt) {
              int m = mh * 32 + mt * 16 + l15;
              st_h(h1, m, nbase,
                   tanh_fast2(acc[nt][mt][0]), tanh_fast2(acc[nt][mt][1]),
                   tanh_fast2(acc[nt][mt][2]), tanh_fast2(acc[nt][mt][3]));
            }
          }
        }
        __syncthreads();                   // (b)

        // G2: h2 = tanh2(h1 @ W1o + b1o), bias in C
        #pragma unroll
        for (int mh = 0; mh < 2; ++mh) {
          floatx4 acc[2][2];
          #pragma unroll
          for (int nt = 0; nt < 2; ++nt) {
            floatx4 bb = *reinterpret_cast<const floatx4*>(pars + 256 + nb + nt * 16 + g * 4);
            acc[nt][0] = bb; acc[nt][1] = bb;
          }
          #pragma unroll
          for (int ks = 0; ks < 8; ++ks) {
            short8 A[2], B[2];
            if (ks < 2) {
              A[0] = aw1h[0][ks]; A[1] = aw1h[1][ks];
            } else {
              A[0] = w1ode[((w * 2 + 0) * 8 + ks) * 64 + lane];
              A[1] = w1ode[((w * 2 + 1) * 8 + ks) * 64 + lane];
            }
            #pragma unroll
            for (int mt = 0; mt < 2; ++mt) {
              int m = mh * 32 + mt * 16 + l15;
              int off = (m * 512 + (ks * 32 + g * 8) * 2) ^ ((m & 15) << 4);
              B[mt] = *reinterpret_cast<const short8*>(h1 + off);
            }
            #pragma unroll
            for (int nt = 0; nt < 2; ++nt)
              #pragma unroll
              for (int mt = 0; mt < 2; ++mt) acc[nt][mt] = MF(A[nt], B[mt], acc[nt][mt]);
          }
          #pragma unroll
          for (int nt = 0; nt < 2; ++nt) {
            int nbase = nb + nt * 16 + g * 4;
            #pragma unroll
            for (int mt = 0; mt < 2; ++mt) {
              int m = mh * 32 + mt * 16 + l15;
              st_h(h2, m, nbase,
                   tanh_fast2(acc[nt][mt][0]), tanh_fast2(acc[nt][mt][1]),
                   tanh_fast2(acc[nt][mt][2]), tanh_fast2(acc[nt][mt][3]));
            }
          }
        }
        __syncthreads();                   // (d')

        // G3: k = h2 @ W2o + b2o, bias in C
        {
          floatx4 a2[2];
          {
            floatx4 b2v = *reinterpret_cast<const floatx4*>(pars + 512 + d0);
            a2[0] = b2v; a2[1] = b2v;
          }
          #pragma unroll
          for (int ks = 0; ks < 8; ++ks) {
            #pragma unroll
            for (int mt = 0; mt < 2; ++mt) {
              int m = wm * 32 + mt * 16 + l15;
              int off = (m * 512 + (ks * 32 + g * 8) * 2) ^ ((m & 15) << 4);
              short8 B = *reinterpret_cast<const short8*>(h2 + off);
              a2[mt] = MF(aw2[ks], B, a2[mt]);
            }
          }
          #pragma unroll
          for (int mt = 0; mt < 2; ++mt)
            #pragma unroll
            for (int p = 0; p < 4; ++p)
              kc[mt * 4 + p] = a2[mt][p];
        }
        if (stg == 0) {
          #pragma unroll
          for (int i = 0; i < 8; ++i) ka[i] = kc[i];
        } else if (stg == 3) {
          #pragma unroll
          for (int i = 0; i < 8; ++i) ka[i] += kc[i];
        } else {
          #pragma unroll
          for (int i = 0; i < 8; ++i) ka[i] += 2.0f * kc[i];
        }
      }
      #pragma unroll
      for (int i = 0; i < 8; ++i) y[i] += (dtv / 6.0f) * ka[i];
    }

    {                                      // BN2
      floatx4 mm = *reinterpret_cast<const floatx4*>(bn2m + l * 64 + d0);
      floatx4 vv = *reinterpret_cast<const floatx4*>(bn2v + l * 64 + d0);
      floatx4 gg = *reinterpret_cast<const floatx4*>(bn2g + l * 64 + d0);
      floatx4 be = *reinterpret_cast<const floatx4*>(bn2b + l * 64 + d0);
      float sc[4];
      #pragma unroll
      for (int p = 0; p < 4; ++p) sc[p] = sqrtf(vv[p] + EPSV) / gg[p];
      #pragma unroll
      for (int mt = 0; mt < 2; ++mt)
        #pragma unroll
        for (int p = 0; p < 4; ++p)
          y[mt * 4 + p] = (y[mt * 4 + p] - be[p]) * sc[p] + mm[p];
    }
  }

  #pragma unroll
  for (int mt = 0; mt < 2; ++mt) {
    int m = wm * 32 + mt * 16 + l15;
    floatx4 v = {y[mt * 4 + 0], y[mt * 4 + 1], y[mt * 4 + 2], y[mt * 4 + 3]};
    *reinterpret_cast<floatx4*>(out + (row0 + m) * 64 + d0) = v;
  }
}

extern "C" void kernel_launch(void* const* d_in, const int* in_sizes, int n_in,
                              void* d_out, int out_size, void* d_ws, size_t ws_size,
                              hipStream_t stream) {
  const float* x      = (const float*)d_in[0];
  const float* nvpW0  = (const float*)d_in[2];
  const float* nvp_b0 = (const float*)d_in[3];
  const float* nvpW1  = (const float*)d_in[4];
  const float* nvp_b1 = (const float*)d_in[5];
  const float* nvpW2  = (const float*)d_in[6];
  const float* nvp_b2 = (const float*)d_in[7];
  const float* odeW0  = (const float*)d_in[8];
  const float* ode_b0 = (const float*)d_in[9];
  const float* odeW1  = (const float*)d_in[10];
  const float* ode_b1 = (const float*)d_in[11];
  const float* odeW2  = (const float*)d_in[12];
  const float* ode_b2 = (const float*)d_in[13];
  const float* bn1m   = (const float*)d_in[14];
  const float* bn1v   = (const float*)d_in[15];
  const float* bn1g   = (const float*)d_in[16];
  const float* bn1b   = (const float*)d_in[17];
  const float* bn2m   = (const float*)d_in[18];
  const float* bn2v   = (const float*)d_in[19];
  const float* bn2g   = (const float*)d_in[20];
  const float* bn2b   = (const float*)d_in[21];
  unsigned short* ws  = (unsigned short*)d_ws;
  float* out          = (float*)d_out;

  int pblocks = (WS_ELEMS + 255) / 256;
  prep_kernel<<<pblocks, 256, 0, stream>>>(odeW0, odeW1, odeW2, nvpW0, nvpW1, nvpW2, ws);
  flow_kernel<<<512, 512, 0, stream>>>(x, nvp_b0, nvp_b1, nvp_b2, odeW0,
                                       ode_b0, ode_b1, ode_b2,
                                       bn1m, bn1v, bn1g, bn1b,
                                       bn2m, bn2v, bn2g, bn2b,
                                       ws, out);
}